// Round 2
// baseline (642.074 us; speedup 1.0000x reference)
//
#include <hip/hip_runtime.h>
#include <hip/hip_bf16.h>

// Problem constants
#define EDIM 1024
#define HHEADS 16
#define DHEAD 64
#define BB 4
#define NSEQ 4096
#define NTOK 16384   // BB*NSEQ

typedef unsigned short u16;
using frag8 = __attribute__((ext_vector_type(8))) short;   // 8 bf16 (4 VGPRs)
using facc4 = __attribute__((ext_vector_type(4))) float;   // 4 f32 acc

__device__ __forceinline__ float b2f(u16 u) {
  union { unsigned int i; float f; } c; c.i = ((unsigned int)u) << 16; return c.f;
}
__device__ __forceinline__ u16 f2b(float f) {
  __hip_bfloat16 h = __float2bfloat16(f);   // RNE
  union { __hip_bfloat16 h; u16 u; } c; c.h = h; return c.u;
}
__device__ __forceinline__ void gl2lds16(const void* g, void* l) {
  __builtin_amdgcn_global_load_lds(
      (const __attribute__((address_space(1))) unsigned int*)g,
      (__attribute__((address_space(3))) unsigned int*)l, 16, 0, 0);
}

// ---------------------------------------------------------------------------
// Dtype probe: inputs are either f32 (per reference) or bf16 (if harness
// converted). Sample u16 at even indices of query_embed: bf16 world -> every
// sample is a bf16 of N(0,1) (exp field in ~[110,129]); f32 world -> samples
// are low mantissa half-words (exp field ~uniform, ~14% inlier).
// flag[0] = 1 -> bf16 world, 0 -> f32 world.
// ---------------------------------------------------------------------------
__global__ void detect_dtype(const u16* __restrict__ src, unsigned* __restrict__ flag) {
  const int lane = threadIdx.x;                    // 64 threads
  const unsigned u = src[(size_t)lane * 200000];   // even indices, < 12.6M
  const unsigned e = (u >> 7) & 0xFF;
  const bool inl = (u == 0) || (e >= 100 && e <= 135);
  const unsigned long long m = __ballot(inl);
  if (lane == 0) flag[0] = (__popcll(m) >= 32) ? 1u : 0u;
}

// Convert n elements (n % 8 == 0) from src (f32 or bf16 per flag) to bf16 dst.
__global__ __launch_bounds__(256) void cvt_bf16(
    const void* __restrict__ src, u16* __restrict__ dst, int n,
    const unsigned* __restrict__ flag) {
  const int i0 = (blockIdx.x * 256 + threadIdx.x) * 8;
  if (i0 >= n) return;
  ushort4 lo, hi;
  if (flag[0] == 0) {
    const float4 a = ((const float4*)src)[i0 >> 2];
    const float4 b = ((const float4*)src)[(i0 >> 2) + 1];
    lo.x = f2b(a.x); lo.y = f2b(a.y); lo.z = f2b(a.z); lo.w = f2b(a.w);
    hi.x = f2b(b.x); hi.y = f2b(b.y); hi.z = f2b(b.z); hi.w = f2b(b.w);
  } else {
    lo = ((const ushort4*)src)[i0 >> 2];
    hi = ((const ushort4*)src)[(i0 >> 2) + 1];
  }
  ((ushort4*)dst)[i0 >> 2] = lo;
  ((ushort4*)dst)[(i0 >> 2) + 1] = hi;
}

// Convert 8 vectors of 1024 elements each (biases, gains, betas).
struct Ptr8 { const void* s[8]; u16* d[8]; };
__global__ __launch_bounds__(256) void cvt8(Ptr8 p, const unsigned* __restrict__ flag) {
  const int t = blockIdx.x * 256 + threadIdx.x;    // 0..1023
  const int v = t >> 7;
  const int i0 = (t & 127) * 8;
  const void* s = p.s[v];
  u16* d = p.d[v];
  ushort4 lo, hi;
  if (flag[0] == 0) {
    const float4 a = ((const float4*)s)[i0 >> 2];
    const float4 b = ((const float4*)s)[(i0 >> 2) + 1];
    lo.x = f2b(a.x); lo.y = f2b(a.y); lo.z = f2b(a.z); lo.w = f2b(a.w);
    hi.x = f2b(b.x); hi.y = f2b(b.y); hi.z = f2b(b.z); hi.w = f2b(b.w);
  } else {
    lo = ((const ushort4*)s)[i0 >> 2];
    hi = ((const ushort4*)s)[(i0 >> 2) + 1];
  }
  ((ushort4*)d)[i0 >> 2] = lo;
  ((ushort4*)d)[(i0 >> 2) + 1] = hi;
}

// ---------------------------------------------------------------------------
// GEMM: C[M,1024] = A[M,1024] @ W[1024,1024]^T + bias (bf16 in, f32 acc).
// outMode=0: bf16 store. outMode=1: f32 store if flag==0 else bf16.
// 128x128 tile, BK=32, 4 waves (2x2), each wave 64x64 via 4x4 MFMA 16x16x32.
// ---------------------------------------------------------------------------
__global__ __launch_bounds__(256, 2) void gemm_bias(
    const u16* __restrict__ A, const u16* __restrict__ W,
    const u16* __restrict__ bias, u16* __restrict__ C,
    const unsigned* __restrict__ flag, int outMode)
{
  __shared__ __align__(16) u16 As[128 * 32];  // row-major [128][32], unpadded (global_load_lds)
  __shared__ __align__(16) u16 Bs[128 * 32];
  const int tid  = threadIdx.x;
  const int lane = tid & 63;
  const int w    = tid >> 6;
  const int wm   = w >> 1, wn = w & 1;
  const int rowBase = blockIdx.x * 128;
  const int colBase = blockIdx.y * 128;

  facc4 acc[4][4];
#pragma unroll
  for (int i = 0; i < 4; ++i)
#pragma unroll
    for (int j = 0; j < 4; ++j) acc[i][j] = (facc4){0.f, 0.f, 0.f, 0.f};

  const int sRow = w * 32 + (lane >> 2);
  const int sCol = (lane & 3) * 8;
  const u16* Ag = A + (size_t)(rowBase + sRow) * EDIM + sCol;
  const u16* Wg = W + (size_t)(colBase + sRow) * EDIM + sCol;
  u16* AsB = As + w * 1024;
  u16* BsB = Bs + w * 1024;

  const int fr = lane & 15;
  const int kq = (lane >> 4) * 8;

  for (int k0 = 0; k0 < EDIM; k0 += 32) {
    gl2lds16(Ag + k0,            AsB);
    gl2lds16(Ag + k0 + 16*EDIM,  AsB + 512);
    gl2lds16(Wg + k0,            BsB);
    gl2lds16(Wg + k0 + 16*EDIM,  BsB + 512);
    __syncthreads();
    frag8 af[4], bf[4];
#pragma unroll
    for (int i = 0; i < 4; ++i)
      af[i] = *(const frag8*)(As + (wm * 64 + i * 16 + fr) * 32 + kq);
#pragma unroll
    for (int j = 0; j < 4; ++j)
      bf[j] = *(const frag8*)(Bs + (wn * 64 + j * 16 + fr) * 32 + kq);
#pragma unroll
    for (int i = 0; i < 4; ++i)
#pragma unroll
      for (int j = 0; j < 4; ++j)
        acc[i][j] = __builtin_amdgcn_mfma_f32_16x16x32_bf16(af[i], bf[j], acc[i][j], 0, 0, 0);
    __syncthreads();
  }

  const bool f32out = (outMode == 1) && (flag[0] == 0);
  float* Cf = (float*)C;
  float bvv[4];
#pragma unroll
  for (int j = 0; j < 4; ++j)
    bvv[j] = b2f(bias[colBase + wn * 64 + j * 16 + fr]);
#pragma unroll
  for (int i = 0; i < 4; ++i) {
#pragma unroll
    for (int r = 0; r < 4; ++r) {
      const int row = rowBase + wm * 64 + i * 16 + (lane >> 4) * 4 + r;  // C/D: row=quad*4+reg
      const size_t ro = (size_t)row * EDIM + colBase + wn * 64 + fr;     // col=lane&15
#pragma unroll
      for (int j = 0; j < 4; ++j) {
        const float val = acc[i][j][r] + bvv[j];
        if (f32out) Cf[ro + j * 16] = val;
        else        C[ro + j * 16]  = f2b(val);
      }
    }
  }
}

// ---------------------------------------------------------------------------
// LayerNorm (+g,beta) then elu+1, per row of 1024 (bf16 in/out, in-place OK).
// ---------------------------------------------------------------------------
__global__ __launch_bounds__(256) void ln_elu(
    const u16* __restrict__ X, const u16* __restrict__ g,
    const u16* __restrict__ beta, u16* __restrict__ Y)
{
  __shared__ float wsum[4], wsq[4];
  const int row = blockIdx.x, tid = threadIdx.x;
  const ushort4 xu = ((const ushort4*)(X + (size_t)row * EDIM))[tid];
  float x[4] = { b2f(xu.x), b2f(xu.y), b2f(xu.z), b2f(xu.w) };
  float s  = x[0] + x[1] + x[2] + x[3];
  float ss = x[0]*x[0] + x[1]*x[1] + x[2]*x[2] + x[3]*x[3];
#pragma unroll
  for (int off = 32; off > 0; off >>= 1) {
    s  += __shfl_down(s,  off, 64);
    ss += __shfl_down(ss, off, 64);
  }
  if ((tid & 63) == 0) { wsum[tid >> 6] = s; wsq[tid >> 6] = ss; }
  __syncthreads();
  const float S  = wsum[0] + wsum[1] + wsum[2] + wsum[3];
  const float SS = wsq[0] + wsq[1] + wsq[2] + wsq[3];
  const float mu  = S * (1.0f / EDIM);
  const float var = SS * (1.0f / EDIM) - mu * mu;
  const float rs  = rsqrtf(var + 1e-5f);
  const ushort4 gu = ((const ushort4*)g)[tid];
  const ushort4 bu = ((const ushort4*)beta)[tid];
  float gg[4] = { b2f(gu.x), b2f(gu.y), b2f(gu.z), b2f(gu.w) };
  float bb[4] = { b2f(bu.x), b2f(bu.y), b2f(bu.z), b2f(bu.w) };
  ushort4 out;
  u16 o[4];
#pragma unroll
  for (int c = 0; c < 4; ++c) {
    float y = (x[c] - mu) * rs * gg[c] + bb[c];
    y = (y > 0.f) ? (y + 1.f) : __expf(y);   // elu(y)+1
    o[c] = f2b(y);
  }
  out.x = o[0]; out.y = o[1]; out.z = o[2]; out.w = o[3];
  ((ushort4*)(Y + (size_t)row * EDIM))[tid] = out;
}

// ---------------------------------------------------------------------------
// kv_sum[bh][d][e] = sum_n k[b,n,h,d]*v[b,n,h,e];  k_sum[bh][d] = sum_n k.
// Grid (8 splits, H, B); wave w takes the n in [w*32,(w+1)*32) slice of each
// 128-n chunk; cross-wave LDS reduction; f32 atomics into KV/Ks.
// ---------------------------------------------------------------------------
#define KVSPLIT 8
__global__ __launch_bounds__(256) void kv_ksum(
    const u16* __restrict__ Km, const u16* __restrict__ V,
    float* __restrict__ KV, float* __restrict__ Ks)
{
  __shared__ __align__(16) u16 kT[64][136];
  __shared__ __align__(16) u16 vT[64][136];
  __shared__ float red[4096];
  const int split = blockIdx.x, h = blockIdx.y, b = blockIdx.z;
  const int bh = b * HHEADS + h;
  const int tid = threadIdx.x, lane = tid & 63, w = tid >> 6;
  const size_t base = (size_t)b * NSEQ * EDIM + h * DHEAD;
  const int nbase = split * (NSEQ / KVSPLIT);   // 512 n per block

  float ksacc[8] = {0, 0, 0, 0, 0, 0, 0, 0};
  facc4 acc[4][4];
#pragma unroll
  for (int i = 0; i < 4; ++i)
#pragma unroll
    for (int j = 0; j < 4; ++j) acc[i][j] = (facc4){0.f, 0.f, 0.f, 0.f};

  const int e0 = (tid & 7) * 8;
  const int nl0 = tid >> 3;      // 0..31
  const int fr = lane & 15;

  for (int c = 0; c < 4; ++c) {
    const int nchunk = nbase + c * 128;
#pragma unroll
    for (int rep = 0; rep < 4; ++rep) {
      const int n = rep * 32 + nl0;
      const uint4 kd = *(const uint4*)(Km + base + (size_t)(nchunk + n) * EDIM + e0);
      const uint4 vd = *(const uint4*)(V  + base + (size_t)(nchunk + n) * EDIM + e0);
      const u16* pk = (const u16*)&kd;
      const u16* pv = (const u16*)&vd;
#pragma unroll
      for (int ii = 0; ii < 8; ++ii) {
        kT[e0 + ii][n] = pk[ii];
        ksacc[ii] += b2f(pk[ii]);
        vT[e0 + ii][n] = pv[ii];
      }
    }
    __syncthreads();
    const int kq2 = w * 32 + (lane >> 4) * 8;
    frag8 af[4], bf[4];
#pragma unroll
    for (int i = 0; i < 4; ++i) af[i] = *(const frag8*)&kT[i * 16 + fr][kq2];
#pragma unroll
    for (int j = 0; j < 4; ++j) bf[j] = *(const frag8*)&vT[j * 16 + fr][kq2];
#pragma unroll
    for (int i = 0; i < 4; ++i)
#pragma unroll
      for (int j = 0; j < 4; ++j)
        acc[i][j] = __builtin_amdgcn_mfma_f32_16x16x32_bf16(af[i], bf[j], acc[i][j], 0, 0, 0);
    __syncthreads();
  }

  for (int ww = 0; ww < 4; ++ww) {
    if (w == ww) {
#pragma unroll
      for (int i = 0; i < 4; ++i)
#pragma unroll
        for (int j = 0; j < 4; ++j)
#pragma unroll
          for (int r = 0; r < 4; ++r) {
            const int d = i * 16 + (lane >> 4) * 4 + r;
            const int e = j * 16 + fr;
            if (ww == 0) red[d * 64 + e] = acc[i][j][r];
            else         red[d * 64 + e] += acc[i][j][r];
          }
    }
    __syncthreads();
  }
#pragma unroll
  for (int ii = 0; ii < 16; ++ii) {
    const int idx = tid + ii * 256;
    atomicAdd(&KV[(size_t)bh * 4096 + idx], red[idx]);
  }
#pragma unroll
  for (int ii = 0; ii < 8; ++ii)
    atomicAdd(&Ks[bh * 64 + e0 + ii], ksacc[ii]);
}

// ---------------------------------------------------------------------------
// attn[b,q,h,e] = (sum_d q[b,q,h,d]*kv[bh][d][e]) / (q . ksum[bh] + 1e-8)
// Grid (NQ/64, H, B); wave handles 16 queries; K=64 => 2 MFMA k-steps.
// ---------------------------------------------------------------------------
__global__ __launch_bounds__(256) void attn_nd(
    const u16* __restrict__ Q, const float* __restrict__ KV,
    const float* __restrict__ Ks, u16* __restrict__ O)
{
  __shared__ __align__(16) u16 kvT[64][72];  // [e][d], pad +8
  __shared__ float ks_s[64];
  __shared__ float den_s[4][16];
  const int qt = blockIdx.x, h = blockIdx.y, b = blockIdx.z;
  const int bh = b * HHEADS + h;
  const int tid = threadIdx.x, lane = tid & 63, w = tid >> 6;
  const float* kvp = KV + (size_t)bh * 4096;
#pragma unroll
  for (int ii = 0; ii < 16; ++ii) {
    const int idx = tid + ii * 256;          // idx = d*64+e
    kvT[idx & 63][idx >> 6] = f2b(kvp[idx]);
  }
  if (tid < 64) ks_s[tid] = Ks[bh * 64 + tid];
  __syncthreads();

  const int fr = lane & 15;
  const int q8 = (lane >> 4) * 8;
  const u16* qp = Q + (size_t)(b * NSEQ + qt * 64 + w * 16 + fr) * EDIM + h * DHEAD;
  const frag8 a0 = *(const frag8*)(qp + q8);
  const frag8 a1 = *(const frag8*)(qp + 32 + q8);

  const u16* a0u = (const u16*)&a0;
  const u16* a1u = (const u16*)&a1;
  float den = 0.f;
#pragma unroll
  for (int j = 0; j < 8; ++j)
    den += b2f(a0u[j]) * ks_s[q8 + j] + b2f(a1u[j]) * ks_s[32 + q8 + j];
  den += __shfl_xor(den, 16, 64);
  den += __shfl_xor(den, 32, 64);
  if (lane < 16) den_s[w][lane] = den + 1e-8f;

  facc4 acc[4];
#pragma unroll
  for (int j = 0; j < 4; ++j) acc[j] = (facc4){0.f, 0.f, 0.f, 0.f};
#pragma unroll
  for (int j = 0; j < 4; ++j) {
    const frag8 b0 = *(const frag8*)&kvT[j * 16 + fr][q8];
    const frag8 b1 = *(const frag8*)&kvT[j * 16 + fr][32 + q8];
    acc[j] = __builtin_amdgcn_mfma_f32_16x16x32_bf16(a0, b0, acc[j], 0, 0, 0);
    acc[j] = __builtin_amdgcn_mfma_f32_16x16x32_bf16(a1, b1, acc[j], 0, 0, 0);
  }
  __syncthreads();
#pragma unroll
  for (int r = 0; r < 4; ++r) {
    const int rq = (lane >> 4) * 4 + r;
    const float dv = den_s[w][rq];
    const size_t orow = (size_t)(b * NSEQ + qt * 64 + w * 16 + rq) * EDIM + h * DHEAD;
#pragma unroll
    for (int j = 0; j < 4; ++j)
      O[orow + j * 16 + fr] = f2b(acc[j][r] / dv);
  }
}

// ---------------------------------------------------------------------------
extern "C" void kernel_launch(void* const* d_in, const int* in_sizes, int n_in,
                              void* d_out, int out_size, void* d_ws, size_t ws_size,
                              hipStream_t stream) {
  char* ws = (char*)d_ws;
  const size_t EH = (size_t)NTOK * EDIM;      // 16.78M elems
  unsigned* flag = (unsigned*)ws;             // 1 KB slot
  u16* Wqb  = (u16*)(ws + 1024);
  u16* Wkb  = Wqb + EDIM * EDIM;
  u16* Wvb  = Wkb + EDIM * EDIM;
  u16* Wob  = Wvb + EDIM * EDIM;
  u16* bqb  = Wob + EDIM * EDIM;
  u16* bkb  = bqb + 1024;
  u16* bvb  = bkb + 1024;
  u16* bob  = bvb + 1024;
  u16* gqb  = bob + 1024;
  u16* bEqb = gqb + 1024;
  u16* gkb  = bEqb + 1024;
  u16* bEkb = gkb + 1024;
  u16* Xin  = bEkb + 1024;    // 33.55 MB staging (qe/ke/va bf16, then attn out)
  u16* preQ = Xin + EH;
  u16* preK = preQ + EH;
  u16* vbuf = preK + EH;
  float* kvbuf = (float*)(vbuf + EH);
  float* ksbuf = kvbuf + 64 * 4096;
  // total ws use ~143.5 MB

  const dim3 gg(NTOK / 128, EDIM / 128), tb(256);
  const int NW = EDIM * EDIM;

  detect_dtype<<<1, 64, 0, stream>>>((const u16*)d_in[0], flag);
  cvt_bf16<<<NW / 2048, 256, 0, stream>>>(d_in[3], Wqb, NW, flag);
  cvt_bf16<<<NW / 2048, 256, 0, stream>>>(d_in[5], Wkb, NW, flag);
  cvt_bf16<<<NW / 2048, 256, 0, stream>>>(d_in[7], Wvb, NW, flag);
  cvt_bf16<<<NW / 2048, 256, 0, stream>>>(d_in[9], Wob, NW, flag);
  Ptr8 p8;
  p8.s[0] = d_in[4];  p8.s[1] = d_in[6];  p8.s[2] = d_in[8];  p8.s[3] = d_in[10];
  p8.s[4] = d_in[11]; p8.s[5] = d_in[12]; p8.s[6] = d_in[13]; p8.s[7] = d_in[14];
  p8.d[0] = bqb; p8.d[1] = bkb; p8.d[2] = bvb; p8.d[3] = bob;
  p8.d[4] = gqb; p8.d[5] = bEqb; p8.d[6] = gkb; p8.d[7] = bEkb;
  cvt8<<<4, 256, 0, stream>>>(p8, flag);

  cvt_bf16<<<EH / 2048, 256, 0, stream>>>(d_in[0], Xin, (int)EH, flag);
  gemm_bias<<<gg, tb, 0, stream>>>(Xin, Wqb, bqb, preQ, flag, 0);
  cvt_bf16<<<EH / 2048, 256, 0, stream>>>(d_in[1], Xin, (int)EH, flag);
  gemm_bias<<<gg, tb, 0, stream>>>(Xin, Wkb, bkb, preK, flag, 0);
  cvt_bf16<<<EH / 2048, 256, 0, stream>>>(d_in[2], Xin, (int)EH, flag);
  gemm_bias<<<gg, tb, 0, stream>>>(Xin, Wvb, bvb, vbuf, flag, 0);

  ln_elu<<<NTOK, 256, 0, stream>>>(preQ, gqb, bEqb, preQ);   // in-place safe
  ln_elu<<<NTOK, 256, 0, stream>>>(preK, gkb, bEkb, preK);

  hipMemsetAsync(kvbuf, 0, (size_t)(64 * 4096 + 64 * 64) * 4, stream);
  kv_ksum<<<dim3(KVSPLIT, HHEADS, BB), tb, 0, stream>>>(preK, vbuf, kvbuf, ksbuf);
  attn_nd<<<dim3(NSEQ / 64, HHEADS, BB), tb, 0, stream>>>(preQ, kvbuf, ksbuf, Xin);
  gemm_bias<<<gg, tb, 0, stream>>>(Xin, Wob, bob, (u16*)d_out, flag, 1);
}

// Round 3
// 542.708 us; speedup vs baseline: 1.1831x; 1.1831x over previous
//
#include <hip/hip_runtime.h>
#include <hip/hip_bf16.h>

// Problem constants
#define EDIM 1024
#define HHEADS 16
#define DHEAD 64
#define BB 4
#define NSEQ 4096
#define NTOK 16384   // BB*NSEQ
#define KVSPLIT 16

typedef unsigned short u16;
using frag8 = __attribute__((ext_vector_type(8))) short;   // 8 bf16 (4 VGPRs)
using facc4 = __attribute__((ext_vector_type(4))) float;   // 4 f32 acc

__device__ __forceinline__ float b2f(u16 u) {
  union { unsigned int i; float f; } c; c.i = ((unsigned int)u) << 16; return c.f;
}
__device__ __forceinline__ u16 f2b(float f) {
  __hip_bfloat16 h = __float2bfloat16(f);   // RNE
  union { __hip_bfloat16 h; u16 u; } c; c.h = h; return c.u;
}
__device__ __forceinline__ void gl2lds16(const void* g, void* l) {
  __builtin_amdgcn_global_load_lds(
      (const __attribute__((address_space(1))) unsigned int*)g,
      (__attribute__((address_space(3))) unsigned int*)l, 16, 0, 0);
}

// ---------------------------------------------------------------------------
// Dtype probe: flag[0]=1 -> inputs are bf16, 0 -> f32 (per reference).
// ---------------------------------------------------------------------------
__global__ void detect_dtype(const u16* __restrict__ src, unsigned* __restrict__ flag) {
  const int lane = threadIdx.x;                    // 64 threads
  const unsigned u = src[(size_t)lane * 200000];   // even u16 indices
  const unsigned e = (u >> 7) & 0xFF;
  const bool inl = (u == 0) || (e >= 100 && e <= 135);
  const unsigned long long m = __ballot(inl);
  if (lane == 0) flag[0] = (__popcll(m) >= 32) ? 1u : 0u;
}

// f32 -> bf16 conversion; NO-OP in bf16 world (GEMM reads raw ptr directly).
__global__ __launch_bounds__(256) void cvt_bf16(
    const void* __restrict__ src, u16* __restrict__ dst, int n,
    const unsigned* __restrict__ flag) {
  if (flag[0] == 1) return;
  const int i0 = (blockIdx.x * 256 + threadIdx.x) * 8;
  if (i0 >= n) return;
  const float4 a = ((const float4*)src)[i0 >> 2];
  const float4 b = ((const float4*)src)[(i0 >> 2) + 1];
  ushort4 lo, hi;
  lo.x = f2b(a.x); lo.y = f2b(a.y); lo.z = f2b(a.z); lo.w = f2b(a.w);
  hi.x = f2b(b.x); hi.y = f2b(b.y); hi.z = f2b(b.z); hi.w = f2b(b.w);
  ((ushort4*)dst)[i0 >> 2] = lo;
  ((ushort4*)dst)[(i0 >> 2) + 1] = hi;
}

// Convert 8 vectors of 1024 elements each (biases, gains, betas). Always runs.
struct Ptr8 { const void* s[8]; u16* d[8]; };
__global__ __launch_bounds__(256) void cvt8(Ptr8 p, const unsigned* __restrict__ flag) {
  const int t = blockIdx.x * 256 + threadIdx.x;    // 0..1023
  const int v = t >> 7;
  const int i0 = (t & 127) * 8;
  const void* s = p.s[v];
  u16* d = p.d[v];
  ushort4 lo, hi;
  if (flag[0] == 0) {
    const float4 a = ((const float4*)s)[i0 >> 2];
    const float4 b = ((const float4*)s)[(i0 >> 2) + 1];
    lo.x = f2b(a.x); lo.y = f2b(a.y); lo.z = f2b(a.z); lo.w = f2b(a.w);
    hi.x = f2b(b.x); hi.y = f2b(b.y); hi.z = f2b(b.z); hi.w = f2b(b.w);
  } else {
    lo = ((const ushort4*)s)[i0 >> 2];
    hi = ((const ushort4*)s)[(i0 >> 2) + 1];
  }
  ((ushort4*)d)[i0 >> 2] = lo;
  ((ushort4*)d)[(i0 >> 2) + 1] = hi;
}

// ---------------------------------------------------------------------------
// GEMM: C[M,1024] = A[M,1024] @ W[1024,1024]^T + bias (bf16 in, f32 acc).
// A/W selected per dtype flag (raw input in bf16 world, converted buffer in
// f32 world). outMode=1: f32 store when flag==0.
// ---------------------------------------------------------------------------
__global__ __launch_bounds__(256, 2) void gemm_bias(
    const void* __restrict__ Araw, const u16* __restrict__ Acvt,
    const void* __restrict__ Wraw, const u16* __restrict__ Wcvt,
    const u16* __restrict__ bias, u16* __restrict__ C,
    const unsigned* __restrict__ flag, int outMode)
{
  __shared__ __align__(16) u16 As[128 * 32];  // row-major [128][32], unpadded (global_load_lds)
  __shared__ __align__(16) u16 Bs[128 * 32];
  const int tid  = threadIdx.x;
  const int lane = tid & 63;
  const int w    = tid >> 6;
  const int wm   = w >> 1, wn = w & 1;
  const int rowBase = blockIdx.x * 128;
  const int colBase = blockIdx.y * 128;

  const bool bfw = (flag[0] == 1);
  const u16* A = bfw ? (const u16*)Araw : Acvt;
  const u16* W = bfw ? (const u16*)Wraw : Wcvt;

  facc4 acc[4][4];
#pragma unroll
  for (int i = 0; i < 4; ++i)
#pragma unroll
    for (int j = 0; j < 4; ++j) acc[i][j] = (facc4){0.f, 0.f, 0.f, 0.f};

  const int sRow = w * 32 + (lane >> 2);
  const int sCol = (lane & 3) * 8;
  const u16* Ag = A + (size_t)(rowBase + sRow) * EDIM + sCol;
  const u16* Wg = W + (size_t)(colBase + sRow) * EDIM + sCol;
  u16* AsB = As + w * 1024;
  u16* BsB = Bs + w * 1024;

  const int fr = lane & 15;
  const int kq = (lane >> 4) * 8;

  for (int k0 = 0; k0 < EDIM; k0 += 32) {
    gl2lds16(Ag + k0,            AsB);
    gl2lds16(Ag + k0 + 16*EDIM,  AsB + 512);
    gl2lds16(Wg + k0,            BsB);
    gl2lds16(Wg + k0 + 16*EDIM,  BsB + 512);
    __syncthreads();
    frag8 af[4], bf[4];
#pragma unroll
    for (int i = 0; i < 4; ++i)
      af[i] = *(const frag8*)(As + (wm * 64 + i * 16 + fr) * 32 + kq);
#pragma unroll
    for (int j = 0; j < 4; ++j)
      bf[j] = *(const frag8*)(Bs + (wn * 64 + j * 16 + fr) * 32 + kq);
#pragma unroll
    for (int i = 0; i < 4; ++i)
#pragma unroll
      for (int j = 0; j < 4; ++j)
        acc[i][j] = __builtin_amdgcn_mfma_f32_16x16x32_bf16(af[i], bf[j], acc[i][j], 0, 0, 0);
    __syncthreads();
  }

  const bool f32out = (outMode == 1) && !bfw;
  float* Cf = (float*)C;
  float bvv[4];
#pragma unroll
  for (int j = 0; j < 4; ++j)
    bvv[j] = b2f(bias[colBase + wn * 64 + j * 16 + fr]);
#pragma unroll
  for (int i = 0; i < 4; ++i) {
#pragma unroll
    for (int r = 0; r < 4; ++r) {
      const int row = rowBase + wm * 64 + i * 16 + (lane >> 4) * 4 + r;  // C/D: row=quad*4+reg
      const size_t ro = (size_t)row * EDIM + colBase + wn * 64 + fr;     // col=lane&15
#pragma unroll
      for (int j = 0; j < 4; ++j) {
        const float val = acc[i][j][r] + bvv[j];
        if (f32out) Cf[ro + j * 16] = val;
        else        C[ro + j * 16]  = f2b(val);
      }
    }
  }
}

// ---------------------------------------------------------------------------
// LayerNorm (+g,beta) then elu+1, per row of 1024 (bf16 in/out, in-place OK).
// ---------------------------------------------------------------------------
__global__ __launch_bounds__(256) void ln_elu(
    const u16* __restrict__ X, const u16* __restrict__ g,
    const u16* __restrict__ beta, u16* __restrict__ Y)
{
  __shared__ float wsum[4], wsq[4];
  const int row = blockIdx.x, tid = threadIdx.x;
  const ushort4 xu = ((const ushort4*)(X + (size_t)row * EDIM))[tid];
  float x[4] = { b2f(xu.x), b2f(xu.y), b2f(xu.z), b2f(xu.w) };
  float s  = x[0] + x[1] + x[2] + x[3];
  float ss = x[0]*x[0] + x[1]*x[1] + x[2]*x[2] + x[3]*x[3];
#pragma unroll
  for (int off = 32; off > 0; off >>= 1) {
    s  += __shfl_down(s,  off, 64);
    ss += __shfl_down(ss, off, 64);
  }
  if ((tid & 63) == 0) { wsum[tid >> 6] = s; wsq[tid >> 6] = ss; }
  __syncthreads();
  const float S  = wsum[0] + wsum[1] + wsum[2] + wsum[3];
  const float SS = wsq[0] + wsq[1] + wsq[2] + wsq[3];
  const float mu  = S * (1.0f / EDIM);
  const float var = SS * (1.0f / EDIM) - mu * mu;
  const float rs  = rsqrtf(var + 1e-5f);
  const ushort4 gu = ((const ushort4*)g)[tid];
  const ushort4 bu = ((const ushort4*)beta)[tid];
  float gg[4] = { b2f(gu.x), b2f(gu.y), b2f(gu.z), b2f(gu.w) };
  float bb[4] = { b2f(bu.x), b2f(bu.y), b2f(bu.z), b2f(bu.w) };
  ushort4 out;
  u16 o[4];
#pragma unroll
  for (int c = 0; c < 4; ++c) {
    float y = (x[c] - mu) * rs * gg[c] + bb[c];
    y = (y > 0.f) ? (y + 1.f) : __expf(y);   // elu(y)+1
    o[c] = f2b(y);
  }
  out.x = o[0]; out.y = o[1]; out.z = o[2]; out.w = o[3];
  ((ushort4*)(Y + (size_t)row * EDIM))[tid] = out;
}

// ---------------------------------------------------------------------------
// Stage 1: per-(split,h,b) partial kv_sum (64x64 f32) + partial k_sum -> own
// global slots (NO atomics). 256 n per block, 2 chunks of 128.
// LDS pitch 130: transpose writes step 8*130 elem = 520 words ≡ 8 (mod 32)
// -> 2-way (free, m136). Cross-wave reduce: rotated regions, all waves active.
// ---------------------------------------------------------------------------
__global__ __launch_bounds__(256) void kv_partial(
    const u16* __restrict__ Km, const u16* __restrict__ V,
    float* __restrict__ partials, float* __restrict__ kspart)
{
  __shared__ __align__(16) u16 smem[2 * 64 * 130];   // kT | vT, 33.3 KB
  u16 (*kT)[130] = (u16(*)[130])smem;
  u16 (*vT)[130] = (u16(*)[130])(smem + 64 * 130);
  float* red = (float*)smem;            // pitch 68; reused after MFMA (<=17.4KB)
  float* ksr = ((float*)smem) + 4352;   // 4 waves x 64 floats

  const int split = blockIdx.x, h = blockIdx.y, b = blockIdx.z;
  const int bh = b * HHEADS + h;
  const int tid = threadIdx.x, lane = tid & 63, w = tid >> 6;
  const size_t base = (size_t)b * NSEQ * EDIM + h * DHEAD;
  const int nbase = split * (NSEQ / KVSPLIT);   // 256 n per block

  float ksacc[8] = {0, 0, 0, 0, 0, 0, 0, 0};
  facc4 acc[4][4];
#pragma unroll
  for (int i = 0; i < 4; ++i)
#pragma unroll
    for (int j = 0; j < 4; ++j) acc[i][j] = (facc4){0.f, 0.f, 0.f, 0.f};

  const int e0 = (tid & 7) * 8;
  const int nl0 = tid >> 3;      // 0..31
  const int fr = lane & 15;
  const int quad = lane >> 4;

  for (int c = 0; c < 2; ++c) {
    const int nchunk = nbase + c * 128;
#pragma unroll
    for (int rep = 0; rep < 4; ++rep) {
      const int n = rep * 32 + nl0;
      const uint4 kd = *(const uint4*)(Km + base + (size_t)(nchunk + n) * EDIM + e0);
      const uint4 vd = *(const uint4*)(V  + base + (size_t)(nchunk + n) * EDIM + e0);
      const u16* pk = (const u16*)&kd;
      const u16* pv = (const u16*)&vd;
#pragma unroll
      for (int ii = 0; ii < 8; ++ii) {
        kT[e0 + ii][n] = pk[ii];
        ksacc[ii] += b2f(pk[ii]);
        vT[e0 + ii][n] = pv[ii];
      }
    }
    __syncthreads();
    const int kq2 = w * 32 + quad * 8;   // wave w contracts n in [w*32,(w+1)*32)
    frag8 af[4], bf[4];
#pragma unroll
    for (int i = 0; i < 4; ++i) af[i] = *(const frag8*)&kT[i * 16 + fr][kq2];
#pragma unroll
    for (int j = 0; j < 4; ++j) bf[j] = *(const frag8*)&vT[j * 16 + fr][kq2];
#pragma unroll
    for (int i = 0; i < 4; ++i)
#pragma unroll
      for (int j = 0; j < 4; ++j)
        acc[i][j] = __builtin_amdgcn_mfma_f32_16x16x32_bf16(af[i], bf[j], acc[i][j], 0, 0, 0);
    __syncthreads();
  }

  // rotated cross-wave reduction into red (pitch 68 -> quad step 272 words ≡ 16: 2-way)
  for (int p = 0; p < 4; ++p) {
    const int j = (w + p) & 3;
#pragma unroll
    for (int i = 0; i < 4; ++i)
#pragma unroll
      for (int r = 0; r < 4; ++r) {
        const int d = i * 16 + quad * 4 + r;
        const int e = j * 16 + fr;
        if (p == 0) red[d * 68 + e] = acc[i][j][r];
        else        red[d * 68 + e] += acc[i][j][r];
      }
    __syncthreads();
  }

  // write 64x64 partial (coalesced)
  const size_t pbase = ((size_t)bh * KVSPLIT + split) * 4096;
#pragma unroll
  for (int ii = 0; ii < 16; ++ii) {
    const int idx = tid + ii * 256;
    partials[pbase + idx] = red[(idx >> 6) * 68 + (idx & 63)];
  }

  // k_sum partial: shuffle-tree over stride-8 lane groups, then cross-wave LDS
#pragma unroll
  for (int ii = 0; ii < 8; ++ii) {
    ksacc[ii] += __shfl_down(ksacc[ii], 32, 64);
    ksacc[ii] += __shfl_down(ksacc[ii], 16, 64);
    ksacc[ii] += __shfl_down(ksacc[ii], 8, 64);
  }
  if (lane < 8) {
#pragma unroll
    for (int ii = 0; ii < 8; ++ii) ksr[w * 64 + lane * 8 + ii] = ksacc[ii];
  }
  __syncthreads();
  if (tid < 64)
    kspart[((size_t)bh * KVSPLIT + split) * 64 + tid] =
        ksr[tid] + ksr[64 + tid] + ksr[128 + tid] + ksr[192 + tid];
}

// Stage 2: reduce KVSPLIT partial slots -> KV f32 [d][e] and Ks.
__global__ __launch_bounds__(256) void kv_reduce(
    const float* __restrict__ partials, const float* __restrict__ kspart,
    float* __restrict__ KV, float* __restrict__ Ks)
{
  const int qt = blockIdx.x;   // 0..3
  const int bh = blockIdx.y;   // 0..63
  const int tid = threadIdx.x;
#pragma unroll
  for (int ii = 0; ii < 4; ++ii) {
    const int idx = qt * 1024 + ii * 256 + tid;
    float s = 0.f;
#pragma unroll
    for (int sp = 0; sp < KVSPLIT; ++sp)
      s += partials[((size_t)bh * KVSPLIT + sp) * 4096 + idx];
    KV[(size_t)bh * 4096 + idx] = s;
  }
  if (qt == 0 && tid < 64) {
    float s = 0.f;
#pragma unroll
    for (int sp = 0; sp < KVSPLIT; ++sp)
      s += kspart[((size_t)bh * KVSPLIT + sp) * 64 + tid];
    Ks[bh * 64 + tid] = s;
  }
}

// ---------------------------------------------------------------------------
// attn[b,q,h,e] = (sum_d q[b,q,h,d]*kv[bh][d][e]) / (q . ksum[bh] + 1e-8)
// ---------------------------------------------------------------------------
__global__ __launch_bounds__(256) void attn_nd(
    const u16* __restrict__ Q, const float* __restrict__ KV,
    const float* __restrict__ Ks, u16* __restrict__ O)
{
  __shared__ __align__(16) u16 kvT[64][72];  // [e][d], pad +8
  __shared__ float ks_s[64];
  __shared__ float den_s[4][16];
  const int qt = blockIdx.x, h = blockIdx.y, b = blockIdx.z;
  const int bh = b * HHEADS + h;
  const int tid = threadIdx.x, lane = tid & 63, w = tid >> 6;
  const float* kvp = KV + (size_t)bh * 4096;
#pragma unroll
  for (int ii = 0; ii < 16; ++ii) {
    const int idx = tid + ii * 256;          // idx = d*64+e
    kvT[idx & 63][idx >> 6] = f2b(kvp[idx]);
  }
  if (tid < 64) ks_s[tid] = Ks[bh * 64 + tid];
  __syncthreads();

  const int fr = lane & 15;
  const int q8 = (lane >> 4) * 8;
  const u16* qp = Q + (size_t)(b * NSEQ + qt * 64 + w * 16 + fr) * EDIM + h * DHEAD;
  const frag8 a0 = *(const frag8*)(qp + q8);
  const frag8 a1 = *(const frag8*)(qp + 32 + q8);

  const u16* a0u = (const u16*)&a0;
  const u16* a1u = (const u16*)&a1;
  float den = 0.f;
#pragma unroll
  for (int j = 0; j < 8; ++j)
    den += b2f(a0u[j]) * ks_s[q8 + j] + b2f(a1u[j]) * ks_s[32 + q8 + j];
  den += __shfl_xor(den, 16, 64);
  den += __shfl_xor(den, 32, 64);
  if (lane < 16) den_s[w][lane] = den + 1e-8f;

  facc4 acc[4];
#pragma unroll
  for (int j = 0; j < 4; ++j) acc[j] = (facc4){0.f, 0.f, 0.f, 0.f};
#pragma unroll
  for (int j = 0; j < 4; ++j) {
    const frag8 b0 = *(const frag8*)&kvT[j * 16 + fr][q8];
    const frag8 b1 = *(const frag8*)&kvT[j * 16 + fr][32 + q8];
    acc[j] = __builtin_amdgcn_mfma_f32_16x16x32_bf16(a0, b0, acc[j], 0, 0, 0);
    acc[j] = __builtin_amdgcn_mfma_f32_16x16x32_bf16(a1, b1, acc[j], 0, 0, 0);
  }
  __syncthreads();
#pragma unroll
  for (int r = 0; r < 4; ++r) {
    const int rq = (lane >> 4) * 4 + r;
    const float dv = den_s[w][rq];
    const size_t orow = (size_t)(b * NSEQ + qt * 64 + w * 16 + rq) * EDIM + h * DHEAD;
#pragma unroll
    for (int j = 0; j < 4; ++j)
      O[orow + j * 16 + fr] = f2b(acc[j][r] / dv);
  }
}

// ---------------------------------------------------------------------------
extern "C" void kernel_launch(void* const* d_in, const int* in_sizes, int n_in,
                              void* d_out, int out_size, void* d_ws, size_t ws_size,
                              hipStream_t stream) {
  char* ws = (char*)d_ws;
  const size_t EH = (size_t)NTOK * EDIM;      // 16.78M elems
  unsigned* flag = (unsigned*)ws;             // 1 KB slot
  u16* Wqb  = (u16*)(ws + 1024);
  u16* Wkb  = Wqb + EDIM * EDIM;
  u16* Wvb  = Wkb + EDIM * EDIM;
  u16* Wob  = Wvb + EDIM * EDIM;
  u16* bqb  = Wob + EDIM * EDIM;
  u16* bkb  = bqb + 1024;
  u16* bvb  = bkb + 1024;
  u16* bob  = bvb + 1024;
  u16* gqb  = bob + 1024;
  u16* bEqb = gqb + 1024;
  u16* gkb  = bEqb + 1024;
  u16* bEkb = gkb + 1024;
  u16* Xin  = bEkb + 1024;    // f32-world staging; later attn output (both worlds)
  u16* preQ = Xin + EH;
  u16* preK = preQ + EH;
  u16* vbuf = preK + EH;
  float* partials = (float*)(vbuf + EH);              // 64*16*4096 f32 = 16MB
  float* kspart   = partials + (size_t)64 * KVSPLIT * 4096;  // 64*16*64 f32
  float* kvbuf    = kspart + (size_t)64 * KVSPLIT * 64;      // 64*4096 f32
  float* ksbuf    = kvbuf + (size_t)64 * 4096;               // 64*64 f32
  // total ws use ~160 MB

  const dim3 gg(NTOK / 128, EDIM / 128), tb(256);
  const int NW = EDIM * EDIM;

  detect_dtype<<<1, 64, 0, stream>>>((const u16*)d_in[0], flag);
  cvt_bf16<<<NW / 2048, 256, 0, stream>>>(d_in[3], Wqb, NW, flag);
  cvt_bf16<<<NW / 2048, 256, 0, stream>>>(d_in[5], Wkb, NW, flag);
  cvt_bf16<<<NW / 2048, 256, 0, stream>>>(d_in[7], Wvb, NW, flag);
  cvt_bf16<<<NW / 2048, 256, 0, stream>>>(d_in[9], Wob, NW, flag);
  Ptr8 p8;
  p8.s[0] = d_in[4];  p8.s[1] = d_in[6];  p8.s[2] = d_in[8];  p8.s[3] = d_in[10];
  p8.s[4] = d_in[11]; p8.s[5] = d_in[12]; p8.s[6] = d_in[13]; p8.s[7] = d_in[14];
  p8.d[0] = bqb; p8.d[1] = bkb; p8.d[2] = bvb; p8.d[3] = bob;
  p8.d[4] = gqb; p8.d[5] = bEqb; p8.d[6] = gkb; p8.d[7] = bEkb;
  cvt8<<<4, 256, 0, stream>>>(p8, flag);

  cvt_bf16<<<EH / 2048, 256, 0, stream>>>(d_in[0], Xin, (int)EH, flag);
  gemm_bias<<<gg, tb, 0, stream>>>(d_in[0], Xin, d_in[3], Wqb, bqb, preQ, flag, 0);
  cvt_bf16<<<EH / 2048, 256, 0, stream>>>(d_in[1], Xin, (int)EH, flag);
  gemm_bias<<<gg, tb, 0, stream>>>(d_in[1], Xin, d_in[5], Wkb, bkb, preK, flag, 0);
  cvt_bf16<<<EH / 2048, 256, 0, stream>>>(d_in[2], Xin, (int)EH, flag);
  gemm_bias<<<gg, tb, 0, stream>>>(d_in[2], Xin, d_in[7], Wvb, bvb, vbuf, flag, 0);

  ln_elu<<<NTOK, 256, 0, stream>>>(preQ, gqb, bEqb, preQ);   // in-place safe
  ln_elu<<<NTOK, 256, 0, stream>>>(preK, gkb, bEkb, preK);

  kv_partial<<<dim3(KVSPLIT, HHEADS, BB), tb, 0, stream>>>(preK, vbuf, partials, kspart);
  kv_reduce<<<dim3(4, 64), tb, 0, stream>>>(partials, kspart, kvbuf, ksbuf);
  attn_nd<<<dim3(NSEQ / 64, HHEADS, BB), tb, 0, stream>>>(preQ, kvbuf, ksbuf, Xin);
  gemm_bias<<<gg, tb, 0, stream>>>(Xin, Xin, d_in[9], Wob, bob, (u16*)d_out, flag, 1);
}